// Round 10
// baseline (244.577 us; speedup 1.0000x reference)
//
#include <hip/hip_runtime.h>
#include <math.h>

#define NB1 8192
#define NB2 12288
#define DD  128
#define KE  768          // effective GEMM K = 6 products x 128
#define NKT 24           // K-tiles of 32

typedef unsigned long long u64;
typedef unsigned short ushort_t;
typedef __attribute__((ext_vector_type(8))) short short8;
typedef __attribute__((ext_vector_type(4))) float f32x4;

__device__ __forceinline__ float bigf() { return __uint_as_float(0x7F7F0000u); }

__device__ __forceinline__ unsigned orderbits(float v) {
    unsigned b = __float_as_uint(v);
    return b ^ ((unsigned)((int)b >> 31) | 0x80000000u);
}
__device__ __forceinline__ float unorderbits(unsigned k) {
    unsigned b = (k & 0x80000000u) ? (k ^ 0x80000000u) : ~k;
    return __uint_as_float(b);
}
__device__ __forceinline__ u64 packkey(float v, unsigned idx) {
    return ((u64)orderbits(v) << 32) | idx;
}
__device__ __forceinline__ u64 umin64(u64 a, u64 b) { return a < b ? a : b; }

__device__ __forceinline__ ushort_t bf_rn(float x) {
    unsigned u = __float_as_uint(x);
    return (ushort_t)((u + 0x7FFFu + ((u >> 16) & 1u)) >> 16);
}
__device__ __forceinline__ float bf_up(ushort_t h) {
    return __uint_as_float(((unsigned)h) << 16);
}

__device__ __forceinline__ void gload_lds16(const void* g, void* l) {
    __builtin_amdgcn_global_load_lds(
        (const __attribute__((address_space(1))) unsigned*)g,
        (__attribute__((address_space(3))) unsigned*)l, 16, 0, 0);
}

// Kernel N: squared norms + init packed min arrays.
__global__ __launch_bounds__(256) void prep_kernel(
    const float* __restrict__ d1, const float* __restrict__ d2,
    float* __restrict__ sq1, float* __restrict__ sq2,
    u64* __restrict__ rowmin, u64* __restrict__ colmin) {
    int t = blockIdx.x * 256 + threadIdx.x;
    if (t < NB1) {
        rowmin[t] = ~0ull;
        const float4* p = (const float4*)(d1 + (size_t)t * DD);
        float s = 0.f;
        #pragma unroll
        for (int c = 0; c < DD / 4; ++c) {
            float4 v = p[c];
            s = fmaf(v.x, v.x, s); s = fmaf(v.y, v.y, s);
            s = fmaf(v.z, v.z, s); s = fmaf(v.w, v.w, s);
        }
        sq1[t] = s;
    }
    if (t < NB2) {
        colmin[t] = ~0ull;
        const float4* p = (const float4*)(d2 + (size_t)t * DD);
        float s = 0.f;
        #pragma unroll
        for (int c = 0; c < DD / 4; ++c) {
            float4 v = p[c];
            s = fmaf(v.x, v.x, s); s = fmaf(v.y, v.y, s);
            s = fmaf(v.z, v.z, s); s = fmaf(v.w, v.w, s);
        }
        sq2[t] = s;
    }
}

// Kernel S2: 3-way bf16 split into K-CONCATENATED row-major planes.
// A'[i][p*128+k] = compA[pa(p)][i][k], B'[j][p*128+k] = compB[pb(p)][j][k]
// with products (pa,pb) = (H,H),(H,M),(M,H),(H,L),(M,M),(L,H):
//   A' row = [H | H | M | H | M | L]   B' row = [H | M | H | L | M | H]
// 4 threads per row, 32 elements each.
__global__ __launch_bounds__(256) void split_gemm_kernel(
    const float* __restrict__ d1, const float* __restrict__ d2,
    ushort_t* __restrict__ Ap, ushort_t* __restrict__ Bp) {
    int t = blockIdx.x * 256 + threadIdx.x;    // 0 .. 81919
    int row = t >> 2, q = t & 3;
    bool isA = row < NB1;
    int r = isA ? row : row - NB1;
    const float* src = (isA ? d1 + (size_t)r * DD : d2 + (size_t)r * DD) + q * 32;
    ushort_t* dst = (isA ? Ap : Bp) + (size_t)r * KE + q * 32;

    #pragma unroll
    for (int v = 0; v < 4; ++v) {
        short8 H, M, L;
        #pragma unroll
        for (int e = 0; e < 8; ++e) {
            float x = src[v * 8 + e];
            ushort_t h = bf_rn(x); float r1 = x - bf_up(h);
            ushort_t m = bf_rn(r1); float r2 = r1 - bf_up(m);
            H[e] = (short)h; M[e] = (short)m; L[e] = (short)bf_rn(r2);
        }
        if (isA) {
            *(short8*)(dst + 0   + v * 8) = H;
            *(short8*)(dst + 128 + v * 8) = H;
            *(short8*)(dst + 384 + v * 8) = H;
            *(short8*)(dst + 256 + v * 8) = M;
            *(short8*)(dst + 512 + v * 8) = M;
            *(short8*)(dst + 640 + v * 8) = L;
        } else {
            *(short8*)(dst + 0   + v * 8) = H;
            *(short8*)(dst + 256 + v * 8) = H;
            *(short8*)(dst + 640 + v * 8) = H;
            *(short8*)(dst + 128 + v * 8) = M;
            *(short8*)(dst + 512 + v * 8) = M;
            *(short8*)(dst + 384 + v * 8) = L;
        }
    }
}

// Kernel T4: phase-scheduled 256x128 GEMM-tile kernel, fused min-reduce.
// 256 threads = 4 waves (2 wr x 2 wc); wave tile 128x64 = acc[8][4] frags.
// K-loop: 24 tiles of BK=32; LDS dbuf A[2][256x32] + B[2][128x32] = 48 KiB
// (2 blocks/CU co-resident for cross-block overlap). Per tile: 2 phases of
// {ds_read frags | issue next-tile global_load_lds -> barrier ->
//  lgkmcnt(0)+sched_barrier -> setprio(1) 16 MFMA setprio(0) -> barrier};
// per-wave vmcnt(0) once per tile, after loads had ~2 phases to land.
// LDS swizzle: slot = g ^ ((r>>1)&3) (16B granules, 64B rows) -> every
// b128 read/write hits the 8-cycle floor. Realized via pre-swizzled
// GLOBAL source + linear gload_lds dest (both-sides rule).
// Race-freedom: buf c^1 is written in iter T only after its tile-(T-1)
// readers drained (in-phase lgkmcnt(0) precedes phase-end barrier).
__global__ __launch_bounds__(256, 2) void mfma_tile4_kernel(
    const ushort_t* __restrict__ Ap, const ushort_t* __restrict__ Bp,
    const float* __restrict__ sq1, const float* __restrict__ sq2,
    u64* __restrict__ rowmin, u64* __restrict__ colmin)
{
    __shared__ __align__(16) short sA[2][8192];   // 2 x 16 KiB
    __shared__ __align__(16) short sB[2][4096];   // 2 x  8 KiB

    // XCD-chunked swizzle: grid 3072 = 8 xcd x 12 chunks x (4i x 8j).
    const int bid = blockIdx.x;
    const int xcd = bid & 7;
    const int t_  = bid >> 3;            // 0..383
    const int ch  = t_ >> 5;             // 0..11
    const int w_  = t_ & 31;
    const int i0b = (xcd * 4 + (w_ >> 3)) * 256;
    const int j0b = (ch * 8 + (w_ & 7)) * 128;

    const int tid  = threadIdx.x;
    const int lane = tid & 63;
    const int wid  = tid >> 6;
    const int wr   = wid >> 1;
    const int wc   = wid & 1;
    const int lrow = lane & 15;
    const int lg   = lane >> 4;

    const int sr4 = tid >> 2;            // staging row within 64-row group
    const int ss  = tid & 3;             // staging slot

    const ushort_t* Asrc = Ap + (size_t)i0b * KE;
    const ushort_t* Bsrc = Bp + (size_t)j0b * KE;

    f32x4 acc[8][4];
    #pragma unroll
    for (int m = 0; m < 8; ++m)
        #pragma unroll
        for (int n = 0; n < 4; ++n)
            acc[m][n] = (f32x4){0.f, 0.f, 0.f, 0.f};

    #define STAGE_A(Ts, cb) do {                                              \
        _Pragma("unroll")                                                     \
        for (int i_ = 0; i_ < 4; ++i_) {                                      \
            int r_ = i_ * 64 + sr4;                                           \
            int g_ = ss ^ ((r_ >> 1) & 3);                                    \
            gload_lds16(Asrc + (size_t)r_ * KE + (Ts) * 32 + g_ * 8,          \
                        &sA[cb][r_ * 32 + ss * 8]);                           \
        } } while (0)
    #define STAGE_B(Ts, cb) do {                                              \
        _Pragma("unroll")                                                     \
        for (int i_ = 0; i_ < 2; ++i_) {                                      \
            int r_ = i_ * 64 + sr4;                                           \
            int g_ = ss ^ ((r_ >> 1) & 3);                                    \
            gload_lds16(Bsrc + (size_t)r_ * KE + (Ts) * 32 + g_ * 8,          \
                        &sB[cb][r_ * 32 + ss * 8]);                           \
        } } while (0)

    // Prologue: stage tile 0 into buf 0.
    STAGE_A(0, 0); STAGE_B(0, 0);
    asm volatile("s_waitcnt vmcnt(0)" ::: "memory");
    __builtin_amdgcn_s_barrier();

    short8 aF[4], bF[4];
    for (int T = 0; T < NKT; ++T) {
        const int c = T & 1;
        // ---------------- phase 0: mi 0-3 ----------------
        #pragma unroll
        for (int n = 0; n < 4; ++n) {
            int r = wc * 64 + n * 16 + lrow;
            bF[n] = *(const short8*)&sB[c][r * 32 + (lg ^ ((r >> 1) & 3)) * 8];
        }
        #pragma unroll
        for (int m = 0; m < 4; ++m) {
            int r = wr * 128 + m * 16 + lrow;
            aF[m] = *(const short8*)&sA[c][r * 32 + (lg ^ ((r >> 1) & 3)) * 8];
        }
        if (T + 1 < NKT) { STAGE_A(T + 1, c ^ 1); STAGE_B(T + 1, c ^ 1); }
        __builtin_amdgcn_s_barrier();
        asm volatile("s_waitcnt lgkmcnt(0)" ::: "memory");
        __builtin_amdgcn_sched_barrier(0);
        __builtin_amdgcn_s_setprio(1);
        #pragma unroll
        for (int m = 0; m < 4; ++m)
            #pragma unroll
            for (int n = 0; n < 4; ++n)
                acc[m][n] = __builtin_amdgcn_mfma_f32_16x16x32_bf16(aF[m], bF[n], acc[m][n], 0, 0, 0);
        __builtin_amdgcn_s_setprio(0);
        __builtin_amdgcn_s_barrier();
        // ---------------- phase 1: mi 4-7 ----------------
        #pragma unroll
        for (int m = 0; m < 4; ++m) {
            int r = wr * 128 + (m + 4) * 16 + lrow;
            aF[m] = *(const short8*)&sA[c][r * 32 + (lg ^ ((r >> 1) & 3)) * 8];
        }
        __builtin_amdgcn_s_barrier();
        asm volatile("s_waitcnt lgkmcnt(0)" ::: "memory");
        __builtin_amdgcn_sched_barrier(0);
        __builtin_amdgcn_s_setprio(1);
        #pragma unroll
        for (int m = 0; m < 4; ++m)
            #pragma unroll
            for (int n = 0; n < 4; ++n)
                acc[m + 4][n] = __builtin_amdgcn_mfma_f32_16x16x32_bf16(aF[m], bF[n], acc[m + 4][n], 0, 0, 0);
        __builtin_amdgcn_s_setprio(0);
        asm volatile("s_waitcnt vmcnt(0)" ::: "memory");
        __builtin_amdgcn_s_barrier();
    }
    #undef STAGE_A
    #undef STAGE_B

    // ---- epilogue: packed-min reductions.
    // C/D frag: row = i0b + wr*128 + mi*16 + 4*lg + r, col = j0b + wc*64 + ni*16 + lrow.
    float q2v[4];
    #pragma unroll
    for (int n = 0; n < 4; ++n)
        q2v[n] = sq2[j0b + wc * 64 + n * 16 + lrow];
    float4 q1v[8];
    #pragma unroll
    for (int m = 0; m < 8; ++m)
        q1v[m] = *(const float4*)(sq1 + i0b + wr * 128 + m * 16 + 4 * lg);

    #pragma unroll
    for (int m = 0; m < 8; ++m)
        #pragma unroll
        for (int r = 0; r < 4; ++r) {
            u64 best = ~0ull;
            #pragma unroll
            for (int n = 0; n < 4; ++n) {
                float kr = fmaf(-2.f, acc[m][n][r], q2v[n]);
                best = umin64(best, packkey(kr, (unsigned)(j0b + wc * 64 + n * 16 + lrow)));
            }
            #pragma unroll
            for (int mask = 8; mask; mask >>= 1)
                best = umin64(best, __shfl_xor(best, mask));
            if (lrow == 0)
                atomicMin(&rowmin[i0b + wr * 128 + m * 16 + 4 * lg + r], best);
        }

    #pragma unroll
    for (int n = 0; n < 4; ++n) {
        u64 best = ~0ull;
        #pragma unroll
        for (int m = 0; m < 8; ++m) {
            const float* q1p = (const float*)&q1v[m];
            #pragma unroll
            for (int r = 0; r < 4; ++r) {
                float kc_ = fmaf(-2.f, acc[m][n][r], q1p[r]);
                best = umin64(best, packkey(kc_, (unsigned)(i0b + wr * 128 + m * 16 + 4 * lg + r)));
            }
        }
        best = umin64(best, __shfl_xor(best, 16));
        best = umin64(best, __shfl_xor(best, 32));
        if (lane < 16)
            atomicMin(&colmin[j0b + wc * 64 + n * 16 + lrow], best);
    }
}

// ===================== fallback path (round-9, ws-size gated) ==============
__global__ __launch_bounds__(256) void split_frag_kernel(
    const float* __restrict__ d1, const float* __restrict__ d2,
    ushort_t* __restrict__ Af, ushort_t* __restrict__ Bf) {
    int t = blockIdx.x * 256 + threadIdx.x;
    int lane = t & 63;
    int task = t >> 6;
    bool isA = task < 2048;
    int lt = isA ? task : task - 2048;
    int rb = lt >> 2;
    int kc = lt & 3;
    int row = rb * 16 + (lane & 15);
    int kst = kc * 32 + (lane >> 4) * 8;
    const float* src = (isA ? d1 : d2) + (size_t)row * DD + kst;
    ushort_t* dst = (isA ? Af : Bf) + ((size_t)lt * 1536 + lane * 8);
    short8 H, M, L;
    #pragma unroll
    for (int e = 0; e < 8; ++e) {
        float x = src[e];
        ushort_t h = bf_rn(x); float r1 = x - bf_up(h);
        ushort_t m = bf_rn(r1); float r2 = r1 - bf_up(m);
        H[e] = (short)h; M[e] = (short)m; L[e] = (short)bf_rn(r2);
    }
    *(short8*)(dst)        = H;
    *(short8*)(dst + 512)  = M;
    *(short8*)(dst + 1024) = L;
}

__device__ __forceinline__ short8 ld8f(const ushort_t* p) { return *(const short8*)p; }

__global__ __launch_bounds__(256) void mfma_tile3_kernel(
    const ushort_t* __restrict__ Af, const ushort_t* __restrict__ Bf,
    const float* __restrict__ sq1, const float* __restrict__ sq2,
    u64* __restrict__ rowmin, u64* __restrict__ colmin)
{
    const int bid  = blockIdx.x;
    const int xcd  = bid & 7;
    const int t_   = bid >> 3;
    const int kch  = t_ >> 6;
    const int wdn  = t_ & 63;
    const int j0b  = (kch * 8 + (wdn & 7)) * 128;
    const int i0b  = (xcd * 8 + (wdn >> 3)) * 128;
    const int tid  = threadIdx.x;
    const int lane = tid & 63;
    const int wid  = tid >> 6;
    const int wr   = wid >> 1;
    const int wc   = wid & 1;
    const int lrow = lane & 15;
    const int lg   = lane >> 4;
    const ushort_t* abase = Af + ((size_t)((i0b >> 4) + wr * 4) * 6144) + lane * 8;
    const ushort_t* bbase = Bf + ((size_t)((j0b >> 4) + wc * 4) * 6144) + lane * 8;

    f32x4 acc[4][4];
    #pragma unroll
    for (int mi = 0; mi < 4; ++mi)
        #pragma unroll
        for (int ni = 0; ni < 4; ++ni)
            acc[mi][ni] = (f32x4){0.f, 0.f, 0.f, 0.f};

    short8 bufA[3][4], bufB[3][4];
    short8 a0[3], a1[3];
    #pragma unroll
    for (int c = 0; c < 3; ++c) {
        #pragma unroll
        for (int ni = 0; ni < 4; ++ni)
            bufA[c][ni] = ld8f(bbase + ni * 6144 + c * 512);
        a0[c] = ld8f(abase + c * 512);
    }
    #pragma unroll
    for (int kc = 0; kc < 4; ++kc) {
        short8 (&bc)[3][4] = (kc & 1) ? bufB : bufA;
        short8 (&bn)[3][4] = (kc & 1) ? bufA : bufB;
        if (kc < 3) {
            #pragma unroll
            for (int c = 0; c < 3; ++c)
                #pragma unroll
                for (int ni = 0; ni < 4; ++ni)
                    bn[c][ni] = ld8f(bbase + ni * 6144 + (kc + 1) * 1536 + c * 512);
        }
        #pragma unroll
        for (int mi = 0; mi < 4; ++mi) {
            if (mi < 3) {
                #pragma unroll
                for (int c = 0; c < 3; ++c)
                    a1[c] = ld8f(abase + (mi + 1) * 6144 + kc * 1536 + c * 512);
            } else if (kc < 3) {
                #pragma unroll
                for (int c = 0; c < 3; ++c)
                    a1[c] = ld8f(abase + (kc + 1) * 1536 + c * 512);
            }
            #pragma unroll
            for (int ni = 0; ni < 4; ++ni) {
                f32x4 a = acc[mi][ni];
                a = __builtin_amdgcn_mfma_f32_16x16x32_bf16(a0[0], bc[0][ni], a, 0, 0, 0);
                a = __builtin_amdgcn_mfma_f32_16x16x32_bf16(a0[0], bc[1][ni], a, 0, 0, 0);
                a = __builtin_amdgcn_mfma_f32_16x16x32_bf16(a0[1], bc[0][ni], a, 0, 0, 0);
                a = __builtin_amdgcn_mfma_f32_16x16x32_bf16(a0[0], bc[2][ni], a, 0, 0, 0);
                a = __builtin_amdgcn_mfma_f32_16x16x32_bf16(a0[1], bc[1][ni], a, 0, 0, 0);
                a = __builtin_amdgcn_mfma_f32_16x16x32_bf16(a0[2], bc[0][ni], a, 0, 0, 0);
                acc[mi][ni] = a;
            }
            #pragma unroll
            for (int c = 0; c < 3; ++c) a0[c] = a1[c];
        }
    }
    float q2v[4];
    #pragma unroll
    for (int ni = 0; ni < 4; ++ni)
        q2v[ni] = sq2[j0b + wc * 64 + ni * 16 + lrow];
    float4 q1v[4];
    #pragma unroll
    for (int mi = 0; mi < 4; ++mi)
        q1v[mi] = *(const float4*)(sq1 + i0b + wr * 64 + mi * 16 + 4 * lg);
    #pragma unroll
    for (int mi = 0; mi < 4; ++mi)
        #pragma unroll
        for (int r = 0; r < 4; ++r) {
            u64 best = ~0ull;
            #pragma unroll
            for (int ni = 0; ni < 4; ++ni) {
                float kr = fmaf(-2.f, acc[mi][ni][r], q2v[ni]);
                best = umin64(best, packkey(kr, (unsigned)(j0b + wc * 64 + ni * 16 + lrow)));
            }
            #pragma unroll
            for (int mask = 8; mask; mask >>= 1)
                best = umin64(best, __shfl_xor(best, mask));
            if (lrow == 0)
                atomicMin(&rowmin[i0b + wr * 64 + mi * 16 + 4 * lg + r], best);
        }
    #pragma unroll
    for (int ni = 0; ni < 4; ++ni) {
        u64 best = ~0ull;
        #pragma unroll
        for (int mi = 0; mi < 4; ++mi) {
            const float* q1p = (const float*)&q1v[mi];
            #pragma unroll
            for (int r = 0; r < 4; ++r) {
                float kc_ = fmaf(-2.f, acc[mi][ni][r], q1p[r]);
                best = umin64(best, packkey(kc_, (unsigned)(i0b + wr * 64 + mi * 16 + 4 * lg + r)));
            }
        }
        best = umin64(best, __shfl_xor(best, 16));
        best = umin64(best, __shfl_xor(best, 32));
        if (lane < 16)
            atomicMin(&colmin[j0b + wc * 64 + ni * 16 + lrow], best);
    }
}

// Kernel 3: assemble outputs (bigf() instead of +inf: inf-inf = NaN fails diff).
__global__ __launch_bounds__(256) void final_kernel(
    const float* __restrict__ sq1,
    const u64* __restrict__ rowmin, const u64* __restrict__ colmin,
    float* __restrict__ out) {
    int i = blockIdx.x * 256 + threadIdx.x;
    if (i >= NB1) return;
    u64 rm = rowmin[i];
    unsigned ju = (unsigned)(rm & 0xFFFFFFFFu);
    float kr = unorderbits((unsigned)(rm >> 32));
    float dist = sqrtf(fmaxf(sq1[i] + kr, 0.f));
    dist = fminf(dist, bigf());
    bool valid = (ju < (unsigned)NB2);
    int j = valid ? (int)ju : 0;
    u64 cm = colmin[j];
    int i2 = (int)(cm & 0xFFFFFFFFu);
    bool mut = valid && (i2 == i);
    out[i] = mut ? dist : bigf();
    out[NB1 + 2 * i]     = mut ? (float)i : -1.f;
    out[NB1 + 2 * i + 1] = mut ? (float)j : -1.f;
    out[NB1 + 2 * NB1 + i] = mut ? 1.f : 0.f;
}

extern "C" void kernel_launch(void* const* d_in, const int* in_sizes, int n_in,
                              void* d_out, int out_size, void* d_ws, size_t ws_size,
                              hipStream_t stream) {
    const float* d1 = (const float*)d_in[0];
    const float* d2 = (const float*)d_in[1];
    float* out = (float*)d_out;

    char* ws = (char*)d_ws;
    float* sq1    = (float*)(ws);
    float* sq2    = (float*)(ws + 32768);
    u64*   rowmin = (u64*)(ws + 81920);
    u64*   colmin = (u64*)(ws + 147456);
    // New path: row-major K-concat planes.
    ushort_t* Ap = (ushort_t*)(ws + 245760);                       // 12,582,912 B
    ushort_t* Bp = (ushort_t*)(ws + 245760 + 12582912);            // 18,874,368 B
    const size_t need2 = 245760 + 12582912 + 18874368;             // ~30.2 MB
    // Fallback path: fragment-major planes (round 9).
    ushort_t* Af = (ushort_t*)(ws + 245760);
    ushort_t* Bf = (ushort_t*)(ws + 245760 + 6291456);
    const size_t need1 = 245760 + 6291456 + 9437184;               // ~15.2 MB

    hipLaunchKernelGGL(prep_kernel, dim3((NB2 + 255) / 256), dim3(256), 0, stream,
                       d1, d2, sq1, sq2, rowmin, colmin);
    if (ws_size >= need2) {
        hipLaunchKernelGGL(split_gemm_kernel, dim3(320), dim3(256), 0, stream,
                           d1, d2, Ap, Bp);
        hipLaunchKernelGGL(mfma_tile4_kernel, dim3(3072), dim3(256), 0, stream,
                           Ap, Bp, sq1, sq2, rowmin, colmin);
    } else if (ws_size >= need1) {
        hipLaunchKernelGGL(split_frag_kernel, dim3(1280), dim3(256), 0, stream,
                           d1, d2, Af, Bf);
        hipLaunchKernelGGL(mfma_tile3_kernel, dim3(6144), dim3(256), 0, stream,
                           Af, Bf, sq1, sq2, rowmin, colmin);
    }
    hipLaunchKernelGGL(final_kernel, dim3((NB1 + 255) / 256), dim3(256), 0, stream,
                       sq1, rowmin, colmin, out);
}